// Round 3
// baseline (311.574 us; speedup 1.0000x reference)
//
#include <hip/hip_runtime.h>
#include <hip/hip_bf16.h>

// LocalBlock: LN1 -> qkv GEMM -> multi-dilate local attn -> +xn -> proj GEMM -> +x
//            -> LN2 -> fc1+gelu -> fc2 -> +x -> transpose out
// B=8 C=384 H=W=56 N=25088 NH=12 hd=32 dils=(1,2,3) HID=1536

#define B_   8
#define C_   384
#define W_   56
#define HW_  3136
#define N_   25088
#define HD_  32
#define HID_ 1536
#define C3_  1152

typedef __attribute__((ext_vector_type(8))) short short8v;
typedef __attribute__((ext_vector_type(4))) float f32x4;

__device__ __forceinline__ float bf2f(unsigned short u) {
  union { float f; unsigned u; } c; c.u = ((unsigned)u) << 16; return c.f;
}
__device__ __forceinline__ unsigned short f2bf(float f) {
  unsigned u = __float_as_uint(f);
  u = (u + 0x7FFFu + ((u >> 16) & 1u)) >> 16;
  return (unsigned short)u;
}

#define GLL(gsrc, ldst) __builtin_amdgcn_global_load_lds( \
    (const __attribute__((address_space(1))) void*)(gsrc), \
    (__attribute__((address_space(3))) void*)(ldst), 16, 0, 0)

// ---------------- weight fp32 -> bf16 ----------------
__global__ void cvt_weights(const float* __restrict__ qw, const float* __restrict__ pw,
                            const float* __restrict__ f1, const float* __restrict__ f2,
                            unsigned short* __restrict__ o) {
  int i = blockIdx.x * 256 + threadIdx.x;
  if (i < 442368)        o[i] = f2bf(qw[i]);
  else if (i < 589824)   o[i] = f2bf(pw[i - 442368]);
  else if (i < 1179648)  o[i] = f2bf(f1[i - 589824]);
  else if (i < 1769472)  o[i] = f2bf(f2[i - 1179648]);
}

// ---------------- x [B,C,HW] -> xp [N,C] (fp32) ----------------
__global__ __launch_bounds__(256)
void transpose_in(const float* __restrict__ x, float* __restrict__ xp) {
  __shared__ float t[32][33];
  const int tx = threadIdx.x, ty = threadIdx.y;
  const int hw0 = blockIdx.x * 32, c0 = blockIdx.y * 32, bz = blockIdx.z;
  const float* xb = x + (size_t)bz * C_ * HW_;
#pragma unroll
  for (int j = 0; j < 4; ++j)
    t[ty + j * 8][tx] = xb[(size_t)(c0 + ty + j * 8) * HW_ + hw0 + tx];
  __syncthreads();
  float* xpb = xp + ((size_t)bz * HW_ + hw0) * C_;
#pragma unroll
  for (int j = 0; j < 4; ++j)
    xpb[(size_t)(ty + j * 8) * C_ + c0 + tx] = t[tx][ty + j * 8];
}

// ---------------- row LayerNorm (fp32 in) -> bf16 out ----------------
__global__ __launch_bounds__(256)
void ln_rows(const float* __restrict__ in, unsigned short* __restrict__ outb,
             const float* __restrict__ g, const float* __restrict__ bb) {
  const int row = blockIdx.x * 4 + (threadIdx.x >> 6);
  const int lane = threadIdx.x & 63;
  const float* rp = in + (size_t)row * C_;
  float v[6]; float s = 0.f, ss = 0.f;
#pragma unroll
  for (int j = 0; j < 6; ++j) { v[j] = rp[lane + j * 64]; s += v[j]; ss += v[j] * v[j]; }
#pragma unroll
  for (int off = 32; off; off >>= 1) { s += __shfl_xor(s, off); ss += __shfl_xor(ss, off); }
  const float mean = s * (1.f / 384.f);
  const float var = ss * (1.f / 384.f) - mean * mean;
  const float rstd = rsqrtf(var + 1e-5f);
  unsigned short* op = outb + (size_t)row * C_;
#pragma unroll
  for (int j = 0; j < 6; ++j) {
    const int c = lane + j * 64;
    op[c] = f2bf((v[j] - mean) * rstd * g[c] + bb[c]);
  }
}

// ---------------- MFMA GEMM: out[M,Nn] = A[M,K](bf16) @ W[Nn,K]^T(bf16) ----------------
// BM=256, BN=128, BK=64. 8 waves as 4M x 2N -> per-wave 64x64, acc[4][4].
// LDS: A slots x3 (32KB each) + B slots x2 (16KB) = 128KB. Counted vmcnt(4):
// A prefetched 2 K-tiles ahead, B 1 ahead; one barrier per iter; 2 kh-phases
// each {ds_read 8 x b128, lgkmcnt(0), setprio(1), 16 MFMA, setprio(0)}.
// LDS rows are 128B (8 x 16B slots), XOR-3 swizzled: slot = gc ^ (row&7),
// applied on pre-swizzled global source (write) and on read (involution).
template <int MODE>
__global__ __launch_bounds__(512, 2)
void gemm256(const unsigned short* __restrict__ A, const unsigned short* __restrict__ Bw,
             const float* __restrict__ bias, const float* resid,
             void* outp, int Nout, int K) {
  __shared__ unsigned short sm[65536];   // 128 KiB
  const int tid = threadIdx.x, l = tid & 63, wv = tid >> 6;
  const int m0 = blockIdx.y * 256, n0 = blockIdx.x * 128;

  // staging source pointers: round r covers rows r*64 + wv*8 + (l>>3),
  // lane stages 16B group s=l&7 whose global col-group is s ^ (row&7)
  const int sub = wv * 8 + (l >> 3);          // row within 64-row round
  const int swz = ((l & 7) ^ ((l >> 3) & 7)) << 3;   // source col elems (row&7 == (l>>3)&7)
  const unsigned short* aSrc0 = A + (size_t)(m0 + 0 * 64 + sub) * K + swz;
  const unsigned short* aSrc1 = A + (size_t)(m0 + 1 * 64 + sub) * K + swz;
  const unsigned short* aSrc2 = A + (size_t)(m0 + 2 * 64 + sub) * K + swz;
  const unsigned short* aSrc3 = A + (size_t)(m0 + 3 * 64 + sub) * K + swz;
  const unsigned short* bSrc0 = Bw + (size_t)(n0 + 0 * 64 + sub) * K + swz;
  const unsigned short* bSrc1 = Bw + (size_t)(n0 + 1 * 64 + sub) * K + swz;
  const int dstOff = wv * 512 + l * 8;        // ushort offset inside a 64-row round

  auto stageA = [&](int t) {
    unsigned short* base = &sm[(t % 3) * 16384 + dstOff];
    const int ko = t * 64;
    GLL(aSrc0 + ko, base);
    GLL(aSrc1 + ko, base + 4096);
    GLL(aSrc2 + ko, base + 8192);
    GLL(aSrc3 + ko, base + 12288);
  };
  auto stageB = [&](int t) {
    unsigned short* base = &sm[49152 + (t & 1) * 8192 + dstOff];
    const int ko = t * 64;
    GLL(bSrc0 + ko, base);
    GLL(bSrc1 + ko, base + 4096);
  };

  const int KT = K >> 6;                      // 6 or 24
  stageA(0); stageB(0); stageA(1);

  const int fr = l & 15, g = l >> 4;
  const int arow = ((wv >> 1) * 64 + fr) * 64;     // + mt*1024
  const int brow = ((wv & 1) * 64 + fr) * 64;      // + nt*1024
  const int sl0 = (g ^ (l & 7)) << 3;              // kh=0 slot (fr&7 == l&7)
  const int sl1 = ((4 + g) ^ (l & 7)) << 3;        // kh=1 slot

  f32x4 acc[4][4] = {};

  for (int t = 0; t < KT; ++t) {
    if (t < KT - 1) asm volatile("s_waitcnt vmcnt(4)" ::: "memory");
    else            asm volatile("s_waitcnt vmcnt(0)" ::: "memory");
    __builtin_amdgcn_sched_barrier(0);
    __builtin_amdgcn_s_barrier();
    __builtin_amdgcn_sched_barrier(0);
    if (t + 1 < KT) stageB(t + 1);
    const unsigned short* sa = &sm[(t % 3) * 16384];
    const unsigned short* sb = &sm[49152 + (t & 1) * 8192];
    short8v af[4], bf[4];
    // ---- kh = 0 ----
#pragma unroll
    for (int mt = 0; mt < 4; ++mt) af[mt] = *(const short8v*)&sa[arow + mt * 1024 + sl0];
#pragma unroll
    for (int nt = 0; nt < 4; ++nt) bf[nt] = *(const short8v*)&sb[brow + nt * 1024 + sl0];
    asm volatile("s_waitcnt lgkmcnt(0)" ::: "memory");
    __builtin_amdgcn_sched_barrier(0);
    __builtin_amdgcn_s_setprio(1);
#pragma unroll
    for (int mt = 0; mt < 4; ++mt)
#pragma unroll
      for (int nt = 0; nt < 4; ++nt)
        acc[mt][nt] = __builtin_amdgcn_mfma_f32_16x16x32_bf16(af[mt], bf[nt], acc[mt][nt], 0, 0, 0);
    __builtin_amdgcn_s_setprio(0);
    __builtin_amdgcn_sched_barrier(0);
    if (t + 2 < KT) stageA(t + 2);
    // ---- kh = 1 ----
#pragma unroll
    for (int mt = 0; mt < 4; ++mt) af[mt] = *(const short8v*)&sa[arow + mt * 1024 + sl1];
#pragma unroll
    for (int nt = 0; nt < 4; ++nt) bf[nt] = *(const short8v*)&sb[brow + nt * 1024 + sl1];
    asm volatile("s_waitcnt lgkmcnt(0)" ::: "memory");
    __builtin_amdgcn_sched_barrier(0);
    __builtin_amdgcn_s_setprio(1);
#pragma unroll
    for (int mt = 0; mt < 4; ++mt)
#pragma unroll
      for (int nt = 0; nt < 4; ++nt)
        acc[mt][nt] = __builtin_amdgcn_mfma_f32_16x16x32_bf16(af[mt], bf[nt], acc[mt][nt], 0, 0, 0);
    __builtin_amdgcn_s_setprio(0);
    __builtin_amdgcn_sched_barrier(0);
  }

  // C/D layout: col = lane&15 (fr) -> n-dim, row = g*4 + j -> m-dim  [measured, guide §3]
  const int g4 = g * 4;
  if (MODE == 3) {
    // transpose whole 256x128 f32 tile through LDS (swizzled), coalesced stores
    __syncthreads();           // all waves done reading K-loop LDS
    float* lf = (float*)sm;    // [col c][row4 u] : addr = c*256 + ((u ^ (c&7))<<2)
#pragma unroll
    for (int mt = 0; mt < 4; ++mt) {
#pragma unroll
      for (int nt = 0; nt < 4; ++nt) {
        const int c = (wv & 1) * 64 + nt * 16 + fr;
        const int ub = (wv >> 1) * 16 + mt * 4 + g;     // row4 index
        const int o = n0 + c;
        const float bo = bias[o];
        f32x4 v = acc[mt][nt];
#pragma unroll
        for (int j = 0; j < 4; ++j)
          v[j] = v[j] + bo + resid[(size_t)(m0 + ub * 4 + j) * C_ + o];
        *(f32x4*)&lf[c * 256 + ((ub ^ (c & 7)) << 2)] = v;
      }
    }
    __syncthreads();
    float* out = (float*)outp;
#pragma unroll
    for (int i = 0; i < 16; ++i) {
      const int c = wv * 16 + i;
      f32x4 v = *(const f32x4*)&lf[c * 256 + ((l ^ (c & 7)) << 2)];
      const int mg = m0 + l * 4;
      const int bb = mg / HW_;
      const int hw = mg - bb * HW_;
      *(f32x4*)&out[((size_t)bb * C_ + n0 + c) * HW_ + hw] = v;
    }
  } else {
#pragma unroll
    for (int mt = 0; mt < 4; ++mt) {
      const int nbase = m0 + (wv >> 1) * 64 + mt * 16 + g4;
#pragma unroll
      for (int nt = 0; nt < 4; ++nt) {
        const int o = n0 + (wv & 1) * 64 + nt * 16 + fr;
#pragma unroll
        for (int j = 0; j < 4; ++j) {
          const int nn = nbase + j;
          const float v = acc[mt][nt][j];
          if (MODE == 0) {
            ((unsigned short*)outp)[(size_t)nn * Nout + o] = f2bf(v);
          } else if (MODE == 1) {
            const size_t ix = (size_t)nn * C_ + o;
            ((float*)outp)[ix] = resid[ix] + v + bias[o];
          } else {
            const float xv = v + bias[o];
            const float gl = 0.5f * xv * (1.f + erff(xv * 0.70710678118f));
            ((unsigned short*)outp)[(size_t)nn * Nout + o] = f2bf(gl);
          }
        }
      }
    }
  }
}

// ---------------- multi-dilate local attention ----------------
__global__ __launch_bounds__(256)
void attn_kernel(const unsigned short* __restrict__ qkv,
                 const unsigned short* __restrict__ xn,
                 unsigned short* __restrict__ aout) {
  const int gid = blockIdx.x * 256 + threadIdx.x;
  const int n = gid / 12;
  const int r = gid - n * 12;
  const int dil = (r >> 2) + 1;
  const int b = n / HW_;
  const int hw = n - b * HW_;
  const int h = hw / W_;
  const int w = hw - h * W_;

  const size_t base = (size_t)n * C3_ + (size_t)r * HD_;
  float q[32];
  {
    const short8v* vp = (const short8v*)(qkv + base);
#pragma unroll
    for (int c8 = 0; c8 < 4; ++c8) {
      short8v v = vp[c8];
#pragma unroll
      for (int e = 0; e < 8; ++e) q[c8 * 8 + e] = bf2f((unsigned short)v[e]);
    }
  }

  float logit[9];
#pragma unroll
  for (int ti = 0; ti < 3; ++ti)
#pragma unroll
    for (int tj = 0; tj < 3; ++tj) {
      const int t = ti * 3 + tj;
      const int hn = h + (ti - 1) * dil, wn = w + (tj - 1) * dil;
      if ((unsigned)hn < 56u && (unsigned)wn < 56u) {
        const int nb = n + (ti - 1) * dil * W_ + (tj - 1) * dil;
        const short8v* kp = (const short8v*)(qkv + (size_t)nb * C3_ + C_ + (size_t)r * HD_);
        float dot = 0.f;
#pragma unroll
        for (int c8 = 0; c8 < 4; ++c8) {
          short8v v = kp[c8];
#pragma unroll
          for (int e = 0; e < 8; ++e) dot += q[c8 * 8 + e] * bf2f((unsigned short)v[e]);
        }
        logit[t] = dot * 0.17677669529663688f;  // 32^-0.5
      } else {
        logit[t] = 0.f;  // zero-padded taps participate with logit 0
      }
    }

  float mx = logit[0];
#pragma unroll
  for (int t = 1; t < 9; ++t) mx = fmaxf(mx, logit[t]);
  float wgt[9]; float se = 0.f;
#pragma unroll
  for (int t = 0; t < 9; ++t) { wgt[t] = __expf(logit[t] - mx); se += wgt[t]; }
  const float inv = 1.f / se;

  float acc[32];
#pragma unroll
  for (int c = 0; c < 32; ++c) acc[c] = 0.f;
#pragma unroll
  for (int ti = 0; ti < 3; ++ti)
#pragma unroll
    for (int tj = 0; tj < 3; ++tj) {
      const int t = ti * 3 + tj;
      const int hn = h + (ti - 1) * dil, wn = w + (tj - 1) * dil;
      if ((unsigned)hn < 56u && (unsigned)wn < 56u) {
        const int nb = n + (ti - 1) * dil * W_ + (tj - 1) * dil;
        const short8v* vp = (const short8v*)(qkv + (size_t)nb * C3_ + 2 * C_ + (size_t)r * HD_);
        const float wt = wgt[t];
#pragma unroll
        for (int c8 = 0; c8 < 4; ++c8) {
          short8v v = vp[c8];
#pragma unroll
          for (int e = 0; e < 8; ++e) acc[c8 * 8 + e] += wt * bf2f((unsigned short)v[e]);
        }
      }
    }

  const size_t obase = (size_t)n * C_ + (size_t)r * HD_;
  const short8v* xv = (const short8v*)(xn + obase);
  short8v ov[4];
#pragma unroll
  for (int c8 = 0; c8 < 4; ++c8) {
    short8v v = xv[c8];
#pragma unroll
    for (int e = 0; e < 8; ++e)
      ov[c8][e] = (short)f2bf(acc[c8 * 8 + e] * inv + bf2f((unsigned short)v[e]));
  }
  short8v* op = (short8v*)(aout + obase);
#pragma unroll
  for (int c8 = 0; c8 < 4; ++c8) op[c8] = ov[c8];
}

extern "C" void kernel_launch(void* const* d_in, const int* in_sizes, int n_in,
                              void* d_out, int out_size, void* d_ws, size_t ws_size,
                              hipStream_t stream) {
  const float* x = (const float*)d_in[0];
  const float* qkv_w = (const float*)d_in[1];
  const float* proj_w = (const float*)d_in[2];
  const float* proj_b = (const float*)d_in[3];
  const float* n1_g = (const float*)d_in[4];
  const float* n1_b = (const float*)d_in[5];
  const float* n2_g = (const float*)d_in[6];
  const float* n2_b = (const float*)d_in[7];
  const float* fc1_w = (const float*)d_in[8];
  const float* fc1_b = (const float*)d_in[9];
  const float* fc2_w = (const float*)d_in[10];
  const float* fc2_b = (const float*)d_in[11];

  char* ws = (char*)d_ws;
  float* xp = (float*)ws;                                        // [N,C] f32
  unsigned short* xn = (unsigned short*)(ws + 38535168);         // [N,C] bf16
  unsigned short* qkvb = (unsigned short*)(ws + 57802752);       // [N,1152] bf16
  unsigned short* abuf = (unsigned short*)(ws + 115605504);      // [N,C] bf16
  unsigned short* hbuf = qkvb;                                   // [N,1536] bf16 (reuse qkv+abuf)
  unsigned short* wq = (unsigned short*)(ws + 134873088);
  unsigned short* wp = wq + 442368;
  unsigned short* wf1 = wp + 147456;
  unsigned short* wf2 = wf1 + 589824;

  cvt_weights<<<6912, 256, 0, stream>>>(qkv_w, proj_w, fc1_w, fc2_w, wq);
  transpose_in<<<dim3(98, 12, 8), dim3(32, 8), 0, stream>>>(x, xp);
  ln_rows<<<6272, 256, 0, stream>>>(xp, xn, n1_g, n1_b);
  // grid: x = n-tiles (BN=128), y = m-tiles (BM=256)
  gemm256<0><<<dim3(9, 98), 512, 0, stream>>>(xn, wq, nullptr, nullptr, qkvb, C3_, C_);
  attn_kernel<<<1176, 256, 0, stream>>>(qkvb, xn, abuf);
  gemm256<1><<<dim3(3, 98), 512, 0, stream>>>(abuf, wp, proj_b, xp, xp, C_, C_);
  ln_rows<<<6272, 256, 0, stream>>>(xp, xn, n2_g, n2_b);
  gemm256<2><<<dim3(12, 98), 512, 0, stream>>>(xn, wf1, fc1_b, nullptr, hbuf, HID_, C_);
  gemm256<3><<<dim3(3, 98), 512, 0, stream>>>(hbuf, wf2, fc2_b, xp, d_out, C_, HID_);
}